// Round 1
// baseline (758.813 us; speedup 1.0000x reference)
//
#include <hip/hip_runtime.h>
#include <hip/hip_bf16.h>

// SNNonLocalBlock: B=16, H=W=64, C=256, L=4096, Ld=1024
//   theta = x@w_theta [B,L,32]; phi = pool(x@w_phi) [B,Ld,32]; g = pool(x@w_g) [B,Ld,128]
//   attn = softmax(theta@phi^T); out = x + sigma*(attn@g @ w_o + b_o)
#define B_  16
#define L_  4096
#define LD  1024
#define D8  32
#define D2  128

static __device__ __forceinline__ float bf16hi_to_f(unsigned int u) {
    return __uint_as_float(u & 0xffff0000u);
}
static __device__ __forceinline__ float bf16lo_to_f(unsigned int u) {
    return __uint_as_float(u << 16);
}

// ---------------------------------------------------------------------------
// K1: fused projection GEMM  out[65536,192] = x[65536,256] @ [w_theta|w_phi|w_g]
// 64-row tiles, BK=32, 256 threads, per-thread 4 rows x 12 cols
// ---------------------------------------------------------------------------
__global__ __launch_bounds__(256) void k_proj(
    const float* __restrict__ x,
    const float* __restrict__ w_theta, const float* __restrict__ w_phi,
    const float* __restrict__ w_g,
    float* __restrict__ theta, float* __restrict__ phi, float* __restrict__ g)
{
    __shared__ float xT[32][68];    // x tile transposed [k][row], pad 68
    __shared__ float Wt[32][192];   // weight tile [k][col]

    const int t = threadIdx.x;
    const int row0 = blockIdx.x * 64;
    const int r0 = (t >> 4) * 4;        // 16 row-groups * 4 rows
    const int c0 = (t & 15) * 12;       // 16 col-groups * 12 cols

    float acc[4][12];
#pragma unroll
    for (int i = 0; i < 4; i++)
#pragma unroll
        for (int j = 0; j < 12; j++) acc[i][j] = 0.f;

    for (int k0 = 0; k0 < 256; k0 += 32) {
        __syncthreads();
#pragma unroll
        for (int i = 0; i < 8; i++) {           // 64 rows x 32 k
            int e = i * 256 + t;
            int r = e >> 5, kk = e & 31;
            xT[kk][r] = x[(size_t)(row0 + r) * 256 + k0 + kk];
        }
#pragma unroll
        for (int i = 0; i < 24; i++) {          // 32 k x 192 cols
            int e = i * 256 + t;
            int kk = e / 192, c = e - kk * 192;
            int krow = k0 + kk;
            float w;
            if (c < 32)       w = w_theta[krow * 32 + c];
            else if (c < 64)  w = w_phi[krow * 32 + (c - 32)];
            else              w = w_g[krow * 128 + (c - 64)];
            Wt[kk][c] = w;
        }
        __syncthreads();
#pragma unroll
        for (int k = 0; k < 32; k++) {
            const float4 a4 = *(const float4*)&xT[k][r0];
            const float4 b0 = *(const float4*)&Wt[k][c0];
            const float4 b1 = *(const float4*)&Wt[k][c0 + 4];
            const float4 b2 = *(const float4*)&Wt[k][c0 + 8];
            const float av[4] = {a4.x, a4.y, a4.z, a4.w};
            const float bv[12] = {b0.x, b0.y, b0.z, b0.w,
                                  b1.x, b1.y, b1.z, b1.w,
                                  b2.x, b2.y, b2.z, b2.w};
#pragma unroll
            for (int i = 0; i < 4; i++)
#pragma unroll
                for (int j = 0; j < 12; j++)
                    acc[i][j] = fmaf(av[i], bv[j], acc[i][j]);
        }
    }

#pragma unroll
    for (int i = 0; i < 4; i++) {
        size_t row = (size_t)(row0 + r0 + i);
#pragma unroll
        for (int j = 0; j < 12; j++) {
            int c = c0 + j;
            float v = acc[i][j];
            if (c < 32)      theta[row * 32 + c] = v;
            else if (c < 64) phi[row * 32 + (c - 32)] = v;
            else             g[row * 128 + (c - 64)] = v;
        }
    }
}

// ---------------------------------------------------------------------------
// K2: 2x2 maxpool.  phi [B,64,64,32]->phi_p [B,1024,32] fp32,
//                   g   [B,64,64,128]->g_p [B,1024,128] bf16
// one thread per pooled output element
// ---------------------------------------------------------------------------
__global__ __launch_bounds__(256) void k_pool(
    const float* __restrict__ phi, const float* __restrict__ g,
    float* __restrict__ phi_p, __hip_bfloat16* __restrict__ g_p)
{
    const int idx = blockIdx.x * 256 + threadIdx.x;
    const int phiN = B_ * LD * D8;           // 524288
    if (idx < phiN) {
        int b = idx / (LD * D8);
        int r = idx - b * (LD * D8);
        int mp = r / D8, k = r - mp * D8;
        int hp = mp >> 5, wp = mp & 31;
        size_t base = ((size_t)b * L_ + (2 * hp) * 64 + 2 * wp) * D8 + k;
        float v0 = phi[base], v1 = phi[base + D8];
        float v2 = phi[base + 64 * D8], v3 = phi[base + 64 * D8 + D8];
        phi_p[idx] = fmaxf(fmaxf(v0, v1), fmaxf(v2, v3));
    } else {
        int j = idx - phiN;                  // < B*LD*D2 = 2097152
        int b = j / (LD * D2);
        int r = j - b * (LD * D2);
        int mp = r / D2, d = r - mp * D2;
        int hp = mp >> 5, wp = mp & 31;
        size_t base = ((size_t)b * L_ + (2 * hp) * 64 + 2 * wp) * D2 + d;
        float v0 = g[base], v1 = g[base + D2];
        float v2 = g[base + 64 * D2], v3 = g[base + 64 * D2 + D2];
        g_p[j] = __float2bfloat16(fmaxf(fmaxf(v0, v1), fmaxf(v2, v3)));
    }
}

// ---------------------------------------------------------------------------
// K3: fused attention per (batch, 32-query tile).
//   loop 8 m-chunks of 128: S=theta@phi^T -> exp -> P(LDS) -> O += P@g (regs)
//   then normalize rows, apply w_o + b_o, residual with x, store.
// 256 threads: 8 q-groups(4 rows) x 32 lanes.
// ---------------------------------------------------------------------------
__global__ __launch_bounds__(256) void k_attn(
    const float* __restrict__ theta, const float* __restrict__ phi_p,
    const __hip_bfloat16* __restrict__ g_p_, const float* __restrict__ x,
    const float* __restrict__ w_o, const float* __restrict__ b_o,
    const float* __restrict__ sigma_p, float* __restrict__ out)
{
    __shared__ float thetaT[32][36];     // [k][q]
    __shared__ float rowsumL[32];
    __shared__ float phiT[32][132];      // [k][m-chunk]; reused as O_lds[32 q][132 d]
    __shared__ float Pl[32][132];        // P chunk [q][m]
    __shared__ unsigned int gL[128][64]; // g chunk [m][d-pairs]; reused as wch[32][256]

    const int t = threadIdx.x;
    const int b = blockIdx.x >> 7;              // /128
    const int q0g = (blockIdx.x & 127) * 32;
    const unsigned int* g32 = (const unsigned int*)g_p_;

    const int g5 = t >> 5;       // q-group 0..7
    const int l5 = t & 31;       // lane in group
    const int qS = g5 * 4;       // this thread's 4 rows (all phases)
    const int mS = l5 * 4;       // S-phase col base within chunk
    const int dO = l5 * 4;       // O-phase col base

    // stage theta tile transposed
#pragma unroll
    for (int i = 0; i < 4; i++) {
        int e = i * 256 + t;
        int q = e >> 5, k = e & 31;
        thetaT[k][q] = theta[((size_t)b * L_ + q0g + q) * D8 + k];
    }
    if (t < 32) rowsumL[t] = 0.f;

    float oacc[4][4];
#pragma unroll
    for (int i = 0; i < 4; i++)
#pragma unroll
        for (int j = 0; j < 4; j++) oacc[i][j] = 0.f;

    for (int mc = 0; mc < 8; mc++) {
        const int m0 = mc * 128;
        __syncthreads();   // previous chunk's readers done (also covers theta stage)
        // stage phi chunk transposed [k][m]
#pragma unroll
        for (int i = 0; i < 16; i++) {
            int e = i * 256 + t;
            int c = e >> 5, k = e & 31;
            phiT[k][c] = phi_p[((size_t)b * LD + m0 + c) * D8 + k];
        }
        // stage g chunk [128][64] u32 (bf16 pairs)
#pragma unroll
        for (int i = 0; i < 32; i++) {
            int e = i * 256 + t;
            int r = e >> 6, p = e & 63;
            gL[r][p] = g32[((size_t)b * LD + m0 + r) * 64 + p];
        }
        __syncthreads();

        // S-phase: s[4 q][4 m]
        float s[4][4];
#pragma unroll
        for (int i = 0; i < 4; i++)
#pragma unroll
            for (int j = 0; j < 4; j++) s[i][j] = 0.f;
#pragma unroll
        for (int k = 0; k < 32; k++) {
            const float4 a4 = *(const float4*)&thetaT[k][qS];
            const float4 p4 = *(const float4*)&phiT[k][mS];
            const float av[4] = {a4.x, a4.y, a4.z, a4.w};
            const float pv[4] = {p4.x, p4.y, p4.z, p4.w};
#pragma unroll
            for (int i = 0; i < 4; i++)
#pragma unroll
                for (int j = 0; j < 4; j++)
                    s[i][j] = fmaf(av[i], pv[j], s[i][j]);
        }

        // exp (scores bounded ~|25| << 88: no max-subtraction needed), P, rowsum
        float part[4];
#pragma unroll
        for (int i = 0; i < 4; i++) {
            float v0 = __expf(s[i][0]), v1 = __expf(s[i][1]);
            float v2 = __expf(s[i][2]), v3 = __expf(s[i][3]);
            part[i] = (v0 + v1) + (v2 + v3);
            float4 w4 = make_float4(v0, v1, v2, v3);
            *(float4*)&Pl[qS + i][mS] = w4;
        }
#pragma unroll
        for (int off = 1; off < 32; off <<= 1) {
#pragma unroll
            for (int i = 0; i < 4; i++)
                part[i] += __shfl_xor(part[i], off);
        }
        if (l5 == 0) {
#pragma unroll
            for (int i = 0; i < 4; i++) rowsumL[qS + i] += part[i];
        }
        __syncthreads();   // P + g ready for all

        // O-phase: oacc[4 q][4 d] += P[q][m] * g[m][d]
#pragma unroll 4
        for (int m = 0; m < 128; m += 2) {
            const uint2 ga = *(const uint2*)&gL[m][l5 * 2];
            const uint2 gb = *(const uint2*)&gL[m + 1][l5 * 2];
            const float g0[4] = {bf16lo_to_f(ga.x), bf16hi_to_f(ga.x),
                                 bf16lo_to_f(ga.y), bf16hi_to_f(ga.y)};
            const float g1[4] = {bf16lo_to_f(gb.x), bf16hi_to_f(gb.x),
                                 bf16lo_to_f(gb.y), bf16hi_to_f(gb.y)};
#pragma unroll
            for (int i = 0; i < 4; i++) {
                const float2 p2 = *(const float2*)&Pl[qS + i][m];
#pragma unroll
                for (int j = 0; j < 4; j++)
                    oacc[i][j] = fmaf(p2.x, g0[j], fmaf(p2.y, g1[j], oacc[i][j]));
            }
        }
    }
    __syncthreads();

    // normalize and park O in LDS (reuse phiT as O_lds [32 q][132 d])
    {
        float rinv[4];
#pragma unroll
        for (int i = 0; i < 4; i++) rinv[i] = 1.0f / rowsumL[qS + i];
#pragma unroll
        for (int i = 0; i < 4; i++) {
            float4 o4 = make_float4(oacc[i][0] * rinv[i], oacc[i][1] * rinv[i],
                                    oacc[i][2] * rinv[i], oacc[i][3] * rinv[i]);
            *(float4*)&phiT[qS + i][dO] = o4;
        }
    }
    __syncthreads();

    // w_o GEMM: out_acc[4 q][8 c] over cols {4*l5..+3} and {128+4*l5..+3}
    float out_acc[4][8];
#pragma unroll
    for (int i = 0; i < 4; i++)
#pragma unroll
        for (int j = 0; j < 8; j++) out_acc[i][j] = 0.f;

    float* wch = (float*)&gL[0][0];   // [32 d][256 c]
    for (int dc = 0; dc < 128; dc += 32) {
        __syncthreads();
#pragma unroll
        for (int i = 0; i < 32; i++) {
            int e = i * 256 + t;
            int dd = e >> 8, c = e & 255;
            wch[dd * 256 + c] = w_o[(size_t)(dc + dd) * 256 + c];
        }
        __syncthreads();
#pragma unroll 8
        for (int dd = 0; dd < 32; dd++) {
            const float a0 = phiT[qS + 0][dc + dd];
            const float a1 = phiT[qS + 1][dc + dd];
            const float a2 = phiT[qS + 2][dc + dd];
            const float a3 = phiT[qS + 3][dc + dd];
            const float4 w0 = *(const float4*)&wch[dd * 256 + 4 * l5];
            const float4 w1 = *(const float4*)&wch[dd * 256 + 128 + 4 * l5];
            const float wv[8] = {w0.x, w0.y, w0.z, w0.w, w1.x, w1.y, w1.z, w1.w};
            const float av[4] = {a0, a1, a2, a3};
#pragma unroll
            for (int i = 0; i < 4; i++)
#pragma unroll
                for (int j = 0; j < 8; j++)
                    out_acc[i][j] = fmaf(av[i], wv[j], out_acc[i][j]);
        }
    }

    // epilogue: out = x + sigma * (out_acc + b_o)
    const float sg = *sigma_p;
    const float4 ba = *(const float4*)&b_o[4 * l5];
    const float4 bb = *(const float4*)&b_o[128 + 4 * l5];
#pragma unroll
    for (int i = 0; i < 4; i++) {
        size_t row = (size_t)b * L_ + q0g + qS + i;
        const float4 xa = *(const float4*)&x[row * 256 + 4 * l5];
        const float4 xb = *(const float4*)&x[row * 256 + 128 + 4 * l5];
        float4 oa, ob;
        oa.x = xa.x + sg * (out_acc[i][0] + ba.x);
        oa.y = xa.y + sg * (out_acc[i][1] + ba.y);
        oa.z = xa.z + sg * (out_acc[i][2] + ba.z);
        oa.w = xa.w + sg * (out_acc[i][3] + ba.w);
        ob.x = xb.x + sg * (out_acc[i][4] + bb.x);
        ob.y = xb.y + sg * (out_acc[i][5] + bb.y);
        ob.z = xb.z + sg * (out_acc[i][6] + bb.z);
        ob.w = xb.w + sg * (out_acc[i][7] + bb.w);
        *(float4*)&out[row * 256 + 4 * l5] = oa;
        *(float4*)&out[row * 256 + 128 + 4 * l5] = ob;
    }
}

// ---------------------------------------------------------------------------
extern "C" void kernel_launch(void* const* d_in, const int* in_sizes, int n_in,
                              void* d_out, int out_size, void* d_ws, size_t ws_size,
                              hipStream_t stream)
{
    const float* x       = (const float*)d_in[0];
    const float* w_theta = (const float*)d_in[1];
    const float* w_phi   = (const float*)d_in[2];
    const float* w_g     = (const float*)d_in[3];
    const float* w_o     = (const float*)d_in[4];
    const float* b_o     = (const float*)d_in[5];
    const float* sigma   = (const float*)d_in[6];
    float* out = (float*)d_out;

    // ws layout (float units): theta 2M | phi 2M | g 8M | phi_p 512K | g_p(bf16) 1M u32
    float* ws     = (float*)d_ws;
    float* theta  = ws;
    float* phi    = ws + 2097152;
    float* g      = ws + 4194304;
    float* phi_p  = ws + 12582912;
    __hip_bfloat16* g_p = (__hip_bfloat16*)(ws + 13107200);
    // total ~54 MB of workspace used

    hipLaunchKernelGGL(k_proj, dim3(1024), dim3(256), 0, stream,
                       x, w_theta, w_phi, w_g, theta, phi, g);
    hipLaunchKernelGGL(k_pool, dim3(10240), dim3(256), 0, stream,
                       phi, g, phi_p, g_p);
    hipLaunchKernelGGL(k_attn, dim3(2048), dim3(256), 0, stream,
                       theta, phi_p, g_p, x, w_o, b_o, sigma, out);
}

// Round 2
// 177.963 us; speedup vs baseline: 4.2639x; 4.2639x over previous
//
#include <hip/hip_runtime.h>
#include <hip/hip_bf16.h>

// SNNonLocalBlock: B=16, H=W=64, C=256, L=4096, Ld=1024
// All GEMMs on MFMA bf16 16x16x32. D-layout: col=lane&15, row=(lane>>4)*4+reg.
// A/B frags use consistent k-map k = (lane>>4)*8 + j (any consistent bijection works).

typedef __attribute__((ext_vector_type(8))) short bf16x8;
typedef __attribute__((ext_vector_type(4))) float f32x4;

#define MFMA16(A,B,C) __builtin_amdgcn_mfma_f32_16x16x32_bf16(A,B,C,0,0,0)

static __device__ __forceinline__ unsigned short f2b(float f) {
    __hip_bfloat16 h = __float2bfloat16(f);
    return *reinterpret_cast<unsigned short*>(&h);
}
static __device__ __forceinline__ float blo(unsigned int u){ return __uint_as_float(u << 16); }
static __device__ __forceinline__ float bhi(unsigned int u){ return __uint_as_float(u & 0xffff0000u); }

// ---------------------------------------------------------------------------
// K0: prep: WT[192 n][256 k] bf16 = [w_theta|w_phi|w_g]^T ; woT[256 c][128 d] bf16
// ---------------------------------------------------------------------------
__global__ void k_prep(const float* __restrict__ w_theta, const float* __restrict__ w_phi,
                       const float* __restrict__ w_g, const float* __restrict__ w_o,
                       unsigned short* __restrict__ WT, unsigned short* __restrict__ woT)
{
    int bid = blockIdx.x, t = threadIdx.x;
    if (bid < 192) {
        int n = bid;
        float v;
        if (n < 32)      v = w_theta[t * 32 + n];
        else if (n < 64) v = w_phi[t * 32 + (n - 32)];
        else             v = w_g[t * 128 + (n - 64)];
        WT[n * 256 + t] = f2b(v);
    } else if (t < 128) {
        int cc = bid - 192;
        woT[cc * 128 + t] = f2b(w_o[t * 256 + cc]);
    }
}

// ---------------------------------------------------------------------------
// K1: proj MFMA: out[65536,192] = x @ W. 128-row blocks, BK=64, 4 waves.
// wave w -> m-tiles {2w, 2w+1}; per wave 2x12 tiles.
// ---------------------------------------------------------------------------
__global__ __launch_bounds__(256) void k_proj(
    const float* __restrict__ x, const unsigned short* __restrict__ WT,
    unsigned short* __restrict__ theta_b, unsigned short* __restrict__ phi_b,
    unsigned short* __restrict__ g_b)
{
    __shared__ unsigned short xT[128 * 64];   // [m][64k] swizzled, 16KB
    __shared__ unsigned short wT[192 * 64];   // [n][64k] swizzled, 24KB
    const int t = threadIdx.x;
    const int w = t >> 6, l = t & 63, G = l >> 4, c = l & 15;
    const size_t row0 = (size_t)blockIdx.x * 128;

    f32x4 acc[2][12];
#pragma unroll
    for (int i = 0; i < 2; i++)
#pragma unroll
        for (int j = 0; j < 12; j++) acc[i][j] = (f32x4){0.f, 0.f, 0.f, 0.f};

    for (int k0 = 0; k0 < 256; k0 += 64) {
        __syncthreads();
#pragma unroll
        for (int it = 0; it < 4; it++) {           // x tile: 128 rows x 8 slots
            int u = it * 256 + t, r = u >> 3, s = u & 7;
            const float* px = x + (row0 + r) * 256 + k0 + s * 8;
            float4 a = *(const float4*)px;
            float4 bq = *(const float4*)(px + 4);
            uint4 v;
            v.x = (unsigned)f2b(a.x) | ((unsigned)f2b(a.y) << 16);
            v.y = (unsigned)f2b(a.z) | ((unsigned)f2b(a.w) << 16);
            v.z = (unsigned)f2b(bq.x) | ((unsigned)f2b(bq.y) << 16);
            v.w = (unsigned)f2b(bq.z) | ((unsigned)f2b(bq.w) << 16);
            *(uint4*)((char*)xT + r * 128 + ((s * 16) ^ ((r & 7) << 4))) = v;
        }
#pragma unroll
        for (int it = 0; it < 6; it++) {           // W tile: 192 rows x 8 slots
            int u = it * 256 + t, r = u >> 3, s = u & 7;
            uint4 v = *(const uint4*)(WT + r * 256 + k0 + s * 8);
            *(uint4*)((char*)wT + r * 128 + ((s * 16) ^ ((r & 7) << 4))) = v;
        }
        __syncthreads();
#pragma unroll
        for (int kin = 0; kin < 2; kin++) {
            int m0r = (2 * w) * 16 + c, m1r = (2 * w + 1) * 16 + c;
            bf16x8 a0 = *(const bf16x8*)((char*)xT + m0r * 128 + ((kin * 64 + G * 16) ^ ((m0r & 7) << 4)));
            bf16x8 a1 = *(const bf16x8*)((char*)xT + m1r * 128 + ((kin * 64 + G * 16) ^ ((m1r & 7) << 4)));
#pragma unroll
            for (int nt = 0; nt < 12; nt++) {
                int nr = nt * 16 + c;
                bf16x8 bv = *(const bf16x8*)((char*)wT + nr * 128 + ((kin * 64 + G * 16) ^ ((nr & 7) << 4)));
                acc[0][nt] = MFMA16(a0, bv, acc[0][nt]);
                acc[1][nt] = MFMA16(a1, bv, acc[1][nt]);
            }
        }
    }
#pragma unroll
    for (int mt = 0; mt < 2; mt++)
#pragma unroll
        for (int nt = 0; nt < 12; nt++)
#pragma unroll
            for (int i = 0; i < 4; i++) {
                size_t row = row0 + (2 * w + mt) * 16 + 4 * G + i;
                unsigned short v = f2b(acc[mt][nt][i]);
                if (nt < 2)      theta_b[row * 32 + nt * 16 + c] = v;
                else if (nt < 4) phi_b[row * 32 + (nt - 2) * 16 + c] = v;
                else             g_b[row * 128 + (nt - 4) * 16 + c] = v;
            }
}

// ---------------------------------------------------------------------------
// K2: 2x2 maxpool on bf16 pairs (u32 granules)
// ---------------------------------------------------------------------------
__global__ __launch_bounds__(256) void k_pool(
    const unsigned short* __restrict__ phi_b, const unsigned short* __restrict__ g_b,
    unsigned short* __restrict__ phi_p, unsigned short* __restrict__ g_p)
{
    const unsigned int* p32 = (const unsigned int*)phi_b;
    const unsigned int* gg32 = (const unsigned int*)g_b;
    unsigned int* pp32 = (unsigned int*)phi_p;
    unsigned int* gp32 = (unsigned int*)g_p;
    int idx = blockIdx.x * 256 + threadIdx.x;
    unsigned int v0, v1, v2, v3; unsigned int* dst;
    if (idx < 262144) {            // phi: B*1024*16 u32
        int b = idx >> 14, r = idx & 16383, pm = r >> 4, d2 = r & 15;
        int hp = pm >> 5, wp = pm & 31;
        size_t base = ((size_t)b * 4096 + (2 * hp) * 64 + 2 * wp) * 16 + d2;
        v0 = p32[base]; v1 = p32[base + 16]; v2 = p32[base + 1024]; v3 = p32[base + 1040];
        dst = pp32 + idx;
    } else {                       // g: B*1024*64 u32
        int j = idx - 262144;
        int b = j >> 16, r = j & 65535, pm = r >> 6, d2 = r & 63;
        int hp = pm >> 5, wp = pm & 31;
        size_t base = ((size_t)b * 4096 + (2 * hp) * 64 + 2 * wp) * 64 + d2;
        v0 = gg32[base]; v1 = gg32[base + 64]; v2 = gg32[base + 4096]; v3 = gg32[base + 4160];
        dst = gp32 + j;
    }
    float lo = fmaxf(fmaxf(blo(v0), blo(v1)), fmaxf(blo(v2), blo(v3)));
    float hi = fmaxf(fmaxf(bhi(v0), bhi(v1)), fmaxf(bhi(v2), bhi(v3)));
    *dst = (unsigned)f2b(lo) | ((unsigned)f2b(hi) << 16);
}

// ---------------------------------------------------------------------------
// K3: fused MFMA flash attention + w_o + residual. Block = (b, 64 q-rows), 4 waves.
// wave w owns q-tile w (16 rows). 8 m-chunks of 128.
// ---------------------------------------------------------------------------
__global__ __launch_bounds__(256) void k_attn(
    const unsigned short* __restrict__ theta_b, const unsigned short* __restrict__ phi_p,
    const unsigned short* __restrict__ g_p, const unsigned short* __restrict__ woT,
    const float* __restrict__ x, const float* __restrict__ b_o,
    const float* __restrict__ sigma_p, float* __restrict__ out)
{
    __shared__ unsigned short theta_l[64 * 64];   // 8KB  [q][64k pad] swz
    __shared__ unsigned short phi_l[128 * 64];    // 16KB [m][64k pad] swz
    __shared__ unsigned short gT_l[128 * 128];    // 32KB [d][m] swz ; reused: woT half [c][d]
    __shared__ unsigned short P_l[64 * 128];      // 16KB [q][m] swz ; reused: O_lds [q][d]

    const int t = threadIdx.x;
    const int w = t >> 6, l = t & 63, G = l >> 4, c = l & 15;
    const int b = blockIdx.x >> 6;
    const int q0 = (blockIdx.x & 63) * 64;
    const unsigned int* g32 = (const unsigned int*)g_p;
    const int qa = w * 16 + c;     // this lane's A-frag row (q-local)

    {   // stage theta [64 rows][32k] -> [64][64pad]
        int r = t >> 2, s = t & 3;
        uint4 v = *(const uint4*)(theta_b + ((size_t)(b * 4096 + q0 + r)) * 32 + s * 8);
        *(uint4*)((char*)theta_l + r * 128 + ((s * 16) ^ ((r & 7) << 4))) = v;
    }

    f32x4 oacc[8];
#pragma unroll
    for (int dt = 0; dt < 8; dt++) oacc[dt] = (f32x4){0.f, 0.f, 0.f, 0.f};
    float ps[4] = {0.f, 0.f, 0.f, 0.f};

    for (int mc = 0; mc < 8; mc++) {
        __syncthreads();           // prev chunk readers done (covers theta stage too)
#pragma unroll
        for (int it = 0; it < 2; it++) {   // stage phi chunk [128][32] -> [128][64pad]
            int u = it * 256 + t, r = u >> 2, s = u & 3;
            uint4 v = *(const uint4*)(phi_p + ((size_t)(b * 1024 + mc * 128 + r)) * 32 + s * 8);
            *(uint4*)((char*)phi_l + r * 128 + ((s * 16) ^ ((r & 7) << 4))) = v;
        }
        // stage gT chunk: transpose g_p[m][128d] -> gT_l[d][128m] via shfl pair-pack
#pragma unroll
        for (int mi = 0; mi < 8; mi++) {
            int m = mi * 16 + w * 4 + G;
            const unsigned int* grow = g32 + ((size_t)(b * 1024 + mc * 128 + m)) * 64;
#pragma unroll
            for (int sub = 0; sub < 4; sub++) {
                unsigned int v = grow[sub * 16 + c];
                unsigned int pv = (unsigned int)__shfl_xor((int)v, 16);   // partner m^1
                int d; unsigned int wv;
                if (m & 1) { d = 2 * (sub * 16 + c) + 1; wv = (pv >> 16) | (v & 0xffff0000u); }
                else       { d = 2 * (sub * 16 + c);     wv = (v & 0xffffu) | (pv << 16); }
                int mp = m & ~1;
                *(unsigned int*)((char*)gT_l + d * 256 + ((mp * 2) ^ ((d & 7) << 4))) = wv;
            }
        }
        __syncthreads();
        // S = theta @ phi^T
        bf16x8 at = *(const bf16x8*)((char*)theta_l + qa * 128 + ((G * 16) ^ ((qa & 7) << 4)));
        f32x4 sacc[8];
#pragma unroll
        for (int mt = 0; mt < 8; mt++) {
            int mr = mt * 16 + c;
            bf16x8 bp = *(const bf16x8*)((char*)phi_l + mr * 128 + ((G * 16) ^ ((mr & 7) << 4)));
            f32x4 z = (f32x4){0.f, 0.f, 0.f, 0.f};
            sacc[mt] = MFMA16(at, bp, z);
        }
        // exp -> P (bf16 LDS) + rowsum partials (no max-sub: |S| << 88)
#pragma unroll
        for (int mt = 0; mt < 8; mt++)
#pragma unroll
            for (int i = 0; i < 4; i++) {
                float p = __expf(sacc[mt][i]);
                ps[i] += p;
                int q = w * 16 + 4 * G + i, m = mt * 16 + c;
                *(unsigned short*)((char*)P_l + q * 256 + ((m * 2) ^ ((q & 7) << 4))) = f2b(p);
            }
        __syncthreads();
        // O += P @ g
#pragma unroll
        for (int ks = 0; ks < 4; ks++) {
            bf16x8 ap = *(const bf16x8*)((char*)P_l + qa * 256 + ((ks * 64 + G * 16) ^ ((qa & 7) << 4)));
#pragma unroll
            for (int dt = 0; dt < 8; dt++) {
                int dr = dt * 16 + c;
                bf16x8 bg = *(const bf16x8*)((char*)gT_l + dr * 256 + ((ks * 64 + G * 16) ^ ((dr & 7) << 4)));
                oacc[dt] = MFMA16(ap, bg, oacc[dt]);
            }
        }
    }
    // rowsum reduce over the 16-lane col dimension
#pragma unroll
    for (int off = 1; off <= 8; off <<= 1)
#pragma unroll
        for (int i = 0; i < 4; i++) ps[i] += __shfl_xor(ps[i], off);
    float rinv[4];
#pragma unroll
    for (int i = 0; i < 4; i++) rinv[i] = 1.0f / ps[i];

    __syncthreads();   // all waves done reading gT_l/P_l
    // normalized O -> O_lds (reuse P_l): [64 q][128 d] bf16
#pragma unroll
    for (int dt = 0; dt < 8; dt++)
#pragma unroll
        for (int i = 0; i < 4; i++) {
            int q = w * 16 + 4 * G + i, d = dt * 16 + c;
            *(unsigned short*)((char*)P_l + q * 256 + ((d * 2) ^ ((q & 7) << 4))) = f2b(oacc[dt][i] * rinv[i]);
        }
    const float sg = *sigma_p;

    for (int half = 0; half < 2; half++) {
        if (half) __syncthreads();         // protect gT_l restage vs half-0 reads
#pragma unroll
        for (int it = 0; it < 8; it++) {   // stage woT half [128 c][128 d] into gT_l
            int u = it * 256 + t, r = u >> 4, s = u & 15;
            uint4 v = *(const uint4*)(woT + (size_t)(half * 128 + r) * 128 + s * 8);
            *(uint4*)((char*)gT_l + r * 256 + ((s * 16) ^ ((r & 7) << 4))) = v;
        }
        __syncthreads();
        f32x4 oa[8];
#pragma unroll
        for (int ct = 0; ct < 8; ct++) oa[ct] = (f32x4){0.f, 0.f, 0.f, 0.f};
#pragma unroll
        for (int ks = 0; ks < 4; ks++) {
            bf16x8 aO = *(const bf16x8*)((char*)P_l + qa * 256 + ((ks * 64 + G * 16) ^ ((qa & 7) << 4)));
#pragma unroll
            for (int ct = 0; ct < 8; ct++) {
                int cr = ct * 16 + c;
                bf16x8 bw = *(const bf16x8*)((char*)gT_l + cr * 256 + ((ks * 64 + G * 16) ^ ((cr & 7) << 4)));
                oa[ct] = MFMA16(aO, bw, oa[ct]);
            }
        }
#pragma unroll
        for (int ct = 0; ct < 8; ct++) {
            int col = half * 128 + ct * 16 + c;
            float bo = b_o[col];
#pragma unroll
            for (int i = 0; i < 4; i++) {
                size_t off = (size_t)(b * 4096 + q0 + w * 16 + 4 * G + i) * 256 + col;
                out[off] = x[off] + sg * (oa[ct][i] + bo);
            }
        }
    }
}

// ---------------------------------------------------------------------------
extern "C" void kernel_launch(void* const* d_in, const int* in_sizes, int n_in,
                              void* d_out, int out_size, void* d_ws, size_t ws_size,
                              hipStream_t stream)
{
    const float* x       = (const float*)d_in[0];
    const float* w_theta = (const float*)d_in[1];
    const float* w_phi   = (const float*)d_in[2];
    const float* w_g     = (const float*)d_in[3];
    const float* w_o     = (const float*)d_in[4];
    const float* b_o     = (const float*)d_in[5];
    const float* sigma   = (const float*)d_in[6];
    float* out = (float*)d_out;

    char* ws = (char*)d_ws;
    unsigned short* theta_b = (unsigned short*)(ws);              //  4 MB [B,4096,32]
    unsigned short* phi_b   = (unsigned short*)(ws + 4194304);    //  4 MB [B,4096,32]
    unsigned short* g_b     = (unsigned short*)(ws + 8388608);    // 16 MB [B,4096,128]
    unsigned short* phi_p   = (unsigned short*)(ws + 25165824);   //  1 MB [B,1024,32]
    unsigned short* g_p     = (unsigned short*)(ws + 26214400);   //  4 MB [B,1024,128]
    unsigned short* WT      = (unsigned short*)(ws + 30408704);   // 96 KB [192,256]
    unsigned short* woT     = (unsigned short*)(ws + 30507008);   // 64 KB [256,128]

    hipLaunchKernelGGL(k_prep, dim3(448), dim3(256), 0, stream,
                       w_theta, w_phi, w_g, w_o, WT, woT);
    hipLaunchKernelGGL(k_proj, dim3(512), dim3(256), 0, stream,
                       x, WT, theta_b, phi_b, g_b);
    hipLaunchKernelGGL(k_pool, dim3(5120), dim3(256), 0, stream,
                       phi_b, g_b, phi_p, g_p);
    hipLaunchKernelGGL(k_attn, dim3(1024), dim3(256), 0, stream,
                       theta_b, phi_p, g_p, woT, x, b_o, sigma, out);
}

// Round 3
// 169.699 us; speedup vs baseline: 4.4715x; 1.0487x over previous
//
#include <hip/hip_runtime.h>
#include <hip/hip_bf16.h>

// SNNonLocalBlock: B=16, H=W=64, C=256, L=4096, Ld=1024
// Round 3: P-in-register flash attention (S^T trick), pre-transposed g,
// swizzled LDS everywhere, T14 async staging, XCD block swizzle.

typedef __attribute__((ext_vector_type(8))) short bf16x8;
typedef __attribute__((ext_vector_type(4))) short bf16x4;
typedef __attribute__((ext_vector_type(4))) float f32x4;

#define MFMA16(A,B,C) __builtin_amdgcn_mfma_f32_16x16x32_bf16(A,B,C,0,0,0)

static __device__ __forceinline__ unsigned short f2b(float f) {
    __hip_bfloat16 h = __float2bfloat16(f);
    return *reinterpret_cast<unsigned short*>(&h);
}
static __device__ __forceinline__ float blo(unsigned int u){ return __uint_as_float(u << 16); }
static __device__ __forceinline__ float bhi(unsigned int u){ return __uint_as_float(u & 0xffff0000u); }

// ---------------------------------------------------------------------------
// K0: prep: WT[192 n][256 k] bf16 = [w_theta|w_phi|w_g]^T ; woT[256 c][128 d] bf16
// ---------------------------------------------------------------------------
__global__ void k_prep(const float* __restrict__ w_theta, const float* __restrict__ w_phi,
                       const float* __restrict__ w_g, const float* __restrict__ w_o,
                       unsigned short* __restrict__ WT, unsigned short* __restrict__ woT)
{
    int bid = blockIdx.x, t = threadIdx.x;
    if (bid < 192) {
        int n = bid;
        float v;
        if (n < 32)      v = w_theta[t * 32 + n];
        else if (n < 64) v = w_phi[t * 32 + (n - 32)];
        else             v = w_g[t * 128 + (n - 64)];
        WT[n * 256 + t] = f2b(v);
    } else if (t < 128) {
        int cc = bid - 192;
        woT[cc * 128 + t] = f2b(w_o[t * 256 + cc]);
    }
}

// ---------------------------------------------------------------------------
// K1: proj MFMA: out[65536,192] = x @ W. 128-row blocks, BK=64, 4 waves.
// (unchanged from round 2 — non-attn kernels were only ~5us combined)
// ---------------------------------------------------------------------------
__global__ __launch_bounds__(256) void k_proj(
    const float* __restrict__ x, const unsigned short* __restrict__ WT,
    unsigned short* __restrict__ theta_b, unsigned short* __restrict__ phi_b,
    unsigned short* __restrict__ g_b)
{
    __shared__ unsigned short xT[128 * 64];   // [m][64k] swizzled, 16KB
    __shared__ unsigned short wT[192 * 64];   // [n][64k] swizzled, 24KB
    const int t = threadIdx.x;
    const int w = t >> 6, l = t & 63, G = l >> 4, c = l & 15;
    const size_t row0 = (size_t)blockIdx.x * 128;

    f32x4 acc[2][12];
#pragma unroll
    for (int i = 0; i < 2; i++)
#pragma unroll
        for (int j = 0; j < 12; j++) acc[i][j] = (f32x4){0.f, 0.f, 0.f, 0.f};

    for (int k0 = 0; k0 < 256; k0 += 64) {
        __syncthreads();
#pragma unroll
        for (int it = 0; it < 4; it++) {           // x tile: 128 rows x 8 slots
            int u = it * 256 + t, r = u >> 3, s = u & 7;
            const float* px = x + (row0 + r) * 256 + k0 + s * 8;
            float4 a = *(const float4*)px;
            float4 bq = *(const float4*)(px + 4);
            uint4 v;
            v.x = (unsigned)f2b(a.x) | ((unsigned)f2b(a.y) << 16);
            v.y = (unsigned)f2b(a.z) | ((unsigned)f2b(a.w) << 16);
            v.z = (unsigned)f2b(bq.x) | ((unsigned)f2b(bq.y) << 16);
            v.w = (unsigned)f2b(bq.z) | ((unsigned)f2b(bq.w) << 16);
            *(uint4*)((char*)xT + r * 128 + ((s * 16) ^ ((r & 7) << 4))) = v;
        }
#pragma unroll
        for (int it = 0; it < 6; it++) {           // W tile: 192 rows x 8 slots
            int u = it * 256 + t, r = u >> 3, s = u & 7;
            uint4 v = *(const uint4*)(WT + r * 256 + k0 + s * 8);
            *(uint4*)((char*)wT + r * 128 + ((s * 16) ^ ((r & 7) << 4))) = v;
        }
        __syncthreads();
#pragma unroll
        for (int kin = 0; kin < 2; kin++) {
            int m0r = (2 * w) * 16 + c, m1r = (2 * w + 1) * 16 + c;
            bf16x8 a0 = *(const bf16x8*)((char*)xT + m0r * 128 + ((kin * 64 + G * 16) ^ ((m0r & 7) << 4)));
            bf16x8 a1 = *(const bf16x8*)((char*)xT + m1r * 128 + ((kin * 64 + G * 16) ^ ((m1r & 7) << 4)));
#pragma unroll
            for (int nt = 0; nt < 12; nt++) {
                int nr = nt * 16 + c;
                bf16x8 bv = *(const bf16x8*)((char*)wT + nr * 128 + ((kin * 64 + G * 16) ^ ((nr & 7) << 4)));
                acc[0][nt] = MFMA16(a0, bv, acc[0][nt]);
                acc[1][nt] = MFMA16(a1, bv, acc[1][nt]);
            }
        }
    }
#pragma unroll
    for (int mt = 0; mt < 2; mt++)
#pragma unroll
        for (int nt = 0; nt < 12; nt++)
#pragma unroll
            for (int i = 0; i < 4; i++) {
                size_t row = row0 + (2 * w + mt) * 16 + 4 * G + i;
                unsigned short v = f2b(acc[mt][nt][i]);
                if (nt < 2)      theta_b[row * 32 + nt * 16 + c] = v;
                else if (nt < 4) phi_b[row * 32 + (nt - 2) * 16 + c] = v;
                else             g_b[row * 128 + (nt - 4) * 16 + c] = v;
            }
}

// ---------------------------------------------------------------------------
// K2: pool. blocks [0,1024): phi -> phi_p [b][1024][32].
//          blocks [1024,1536): g -> pooled + TRANSPOSED g_pT [b][128 d][1024 m]
// ---------------------------------------------------------------------------
__global__ __launch_bounds__(256) void k_pool(
    const unsigned short* __restrict__ phi_b, const unsigned short* __restrict__ g_b,
    unsigned short* __restrict__ phi_p, unsigned short* __restrict__ g_pT)
{
    const int bid = blockIdx.x, t = threadIdx.x;
    if (bid < 1024) {
        const unsigned int* p32 = (const unsigned int*)phi_b;
        unsigned int* pp32 = (unsigned int*)phi_p;
        int idx = bid * 256 + t;
        int b = idx >> 14, r = idx & 16383, pm = r >> 4, d2 = r & 15;
        int hp = pm >> 5, wp = pm & 31;
        size_t base = ((size_t)b * 4096 + (2 * hp) * 64 + 2 * wp) * 16 + d2;
        unsigned v0 = p32[base], v1 = p32[base + 16], v2 = p32[base + 1024], v3 = p32[base + 1040];
        float lo = fmaxf(fmaxf(blo(v0), blo(v1)), fmaxf(blo(v2), blo(v3)));
        float hi = fmaxf(fmaxf(bhi(v0), bhi(v1)), fmaxf(bhi(v2), bhi(v3)));
        pp32[idx] = (unsigned)f2b(lo) | ((unsigned)f2b(hi) << 16);
    } else {
        __shared__ unsigned short P[32 * 128];   // [wp][128 d], rows 256B, swz key (wp&7)<<4
        int b = (bid - 1024) >> 5, hp = (bid - 1024) & 31;
        const unsigned int* g32 = (const unsigned int*)g_b;
#pragma unroll
        for (int it = 0; it < 8; it++) {
            int u = it * 256 + t, wp = u >> 6, d2 = u & 63;
            size_t base = ((size_t)b * 4096 + (2 * hp) * 64 + 2 * wp) * 64 + d2;
            unsigned v0 = g32[base], v1 = g32[base + 64], v2 = g32[base + 4096], v3 = g32[base + 4160];
            float lo = fmaxf(fmaxf(blo(v0), blo(v1)), fmaxf(blo(v2), blo(v3)));
            float hi = fmaxf(fmaxf(bhi(v0), bhi(v1)), fmaxf(bhi(v2), bhi(v3)));
            unsigned pv = (unsigned)f2b(lo) | ((unsigned)f2b(hi) << 16);
            *(unsigned*)((char*)P + wp * 256 + ((d2 * 4) ^ ((wp & 7) << 4))) = pv;
        }
        __syncthreads();
#pragma unroll
        for (int it = 0; it < 2; it++) {
            int d = t & 127, s4 = (t >> 7) + it * 2;
            union { unsigned short v[8]; uint4 q; } pk;
#pragma unroll
            for (int k = 0; k < 8; k++) {
                int wp = s4 * 8 + k;
                pk.v[k] = *(const unsigned short*)((char*)P + wp * 256 + ((d * 2) ^ ((wp & 7) << 4)));
            }
            *(uint4*)(g_pT + ((size_t)b * 128 + d) * 1024 + hp * 32 + s4 * 8) = pk.q;
        }
    }
}

// ---------------------------------------------------------------------------
// K3: fused flash attention, P-in-registers. Block = 128 threads (2 waves),
// 64 q rows (32 per wave). 16 m-chunks of 64. Then w_o + bias + residual.
// ---------------------------------------------------------------------------
__global__ __launch_bounds__(128) void k_attn(
    const unsigned short* __restrict__ theta_b, const unsigned short* __restrict__ phi_p,
    const unsigned short* __restrict__ g_pT, const unsigned short* __restrict__ woT,
    const float* __restrict__ x, const float* __restrict__ b_o,
    const float* __restrict__ sigma_p, float* __restrict__ out)
{
    __shared__ uint4 smem4[2048];   // 32 KB
    unsigned short* gT_l    = (unsigned short*)smem4;           // [128 d][64 m] swz, 16KB
    unsigned short* phi_l   = (unsigned short*)(smem4 + 1024);  // [64 m][32 ch], 4KB
    unsigned short* theta_l = (unsigned short*)(smem4 + 1280);  // [64 q][32 ch], 4KB
    unsigned short* O_l     = (unsigned short*)smem4;           // epi: [64 q][128 d] swz, 16KB
    unsigned short* wo_l    = (unsigned short*)(smem4 + 1024);  // epi: [64 c][128 d] swz, 16KB

    const int t = threadIdx.x;
    const int w = t >> 6, l = t & 63, G = l >> 4, c = l & 15;
    // XCD-aware swizzle (1024 % 8 == 0 -> bijective)
    const int bid = (blockIdx.x & 7) * 128 + (blockIdx.x >> 3);
    const int b = bid >> 6;
    const int q0 = (bid & 63) * 64;
    const int xr = (c & 7) << 4;      // gT row swizzle key (d&7 == c&7 for d=dt*16+c)

    // stage theta [64][32]
#pragma unroll
    for (int it = 0; it < 2; it++) {
        int u = it * 128 + t, r = u >> 2, s = u & 3;
        uint4 v = *(const uint4*)(theta_b + ((size_t)(b * 4096 + q0 + r)) * 32 + s * 8);
        *(uint4*)((char*)theta_l + r * 64 + s * 16) = v;
    }

    // chunk-0 global loads (T14: loads live in regs, written after barrier)
    uint4 rphi[2], rgt[8];
#define LOAD_CHUNK(MC)                                                              \
    {                                                                               \
        _Pragma("unroll")                                                           \
        for (int it = 0; it < 2; it++) {                                            \
            int u = it * 128 + t, r = u >> 2, s = u & 3;                            \
            rphi[it] = *(const uint4*)(phi_p + ((size_t)(b * 1024 + (MC) * 64 + r)) * 32 + s * 8); \
        }                                                                           \
        _Pragma("unroll")                                                           \
        for (int it = 0; it < 8; it++) {                                            \
            int u = it * 128 + t, d = u >> 3, s = u & 7;                            \
            rgt[it] = *(const uint4*)(g_pT + ((size_t)(b * 128 + d)) * 1024 + (MC) * 64 + s * 8); \
        }                                                                           \
    }
    LOAD_CHUNK(0);
    __syncthreads();

    // theta B-frags (loop-invariant)
    bf16x8 bt0 = *(const bf16x8*)((char*)theta_l + (w * 32 + c) * 64 + G * 16);
    bf16x8 bt1 = *(const bf16x8*)((char*)theta_l + (w * 32 + 16 + c) * 64 + G * 16);

    f32x4 oacc[2][8];
#pragma unroll
    for (int qt = 0; qt < 2; qt++)
#pragma unroll
        for (int dt = 0; dt < 8; dt++) oacc[qt][dt] = (f32x4){0.f, 0.f, 0.f, 0.f};
    float ps[2] = {0.f, 0.f};
    const f32x4 zf = (f32x4){0.f, 0.f, 0.f, 0.f};

    for (int mc = 0; mc < 16; mc++) {
        __syncthreads();                     // consumers of previous chunk done
#pragma unroll
        for (int it = 0; it < 2; it++) {     // write phi chunk
            int u = it * 128 + t, r = u >> 2, s = u & 3;
            *(uint4*)((char*)phi_l + r * 64 + s * 16) = rphi[it];
        }
#pragma unroll
        for (int it = 0; it < 8; it++) {     // write gT chunk (swizzled)
            int u = it * 128 + t, d = u >> 3, s = u & 7;
            *(uint4*)((char*)gT_l + d * 128 + ((s * 16) ^ ((d & 7) << 4))) = rgt[it];
        }
        __syncthreads();
        if (mc < 15) LOAD_CHUNK(mc + 1);     // overlap next loads with compute

        // S^T = phi @ theta^T : lane (G,c) gets S[m = mt*16+4G+i][q = c]
        bf16x8 ap[4];
#pragma unroll
        for (int mt = 0; mt < 4; mt++)
            ap[mt] = *(const bf16x8*)((char*)phi_l + (mt * 16 + c) * 64 + G * 16);
        f32x4 sacc[2][4];
#pragma unroll
        for (int mt = 0; mt < 4; mt++) {
            sacc[0][mt] = MFMA16(ap[mt], bt0, zf);
            sacc[1][mt] = MFMA16(ap[mt], bt1, zf);
        }

        // exp (no max-sub: |S| <~ 30 << 88) -> packed P A-frags + rowsum partials
        bf16x8 pa[2][2];
#pragma unroll
        for (int qt = 0; qt < 2; qt++) {
#pragma unroll
            for (int ks = 0; ks < 2; ks++) {
                union { unsigned u[4]; bf16x8 v; } pu;
#pragma unroll
                for (int hf = 0; hf < 2; hf++) {
                    int mt = 2 * ks + hf;
                    float p0 = __expf(sacc[qt][mt][0]);
                    float p1 = __expf(sacc[qt][mt][1]);
                    float p2 = __expf(sacc[qt][mt][2]);
                    float p3 = __expf(sacc[qt][mt][3]);
                    ps[qt] += (p0 + p1) + (p2 + p3);
                    pu.u[hf * 2]     = (unsigned)f2b(p0) | ((unsigned)f2b(p1) << 16);
                    pu.u[hf * 2 + 1] = (unsigned)f2b(p2) | ((unsigned)f2b(p3) << 16);
                }
                pa[qt][ks] = pu.v;
            }
        }

        // O += P @ g  (B-frag: two b64 reads, k-map matches register P layout)
#pragma unroll
        for (int ks = 0; ks < 2; ks++) {
#pragma unroll
            for (int dt = 0; dt < 8; dt++) {
                const char* rb = (const char*)gT_l + (dt * 16 + c) * 128;
                bf16x4 x0 = *(const bf16x4*)(rb + ((64 * ks + 8 * G) ^ xr));
                bf16x4 x1 = *(const bf16x4*)(rb + ((64 * ks + 32 + 8 * G) ^ xr));
                bf16x8 bg = __builtin_shufflevector(x0, x1, 0, 1, 2, 3, 4, 5, 6, 7);
                oacc[0][dt] = MFMA16(pa[0][ks], bg, oacc[0][dt]);
                oacc[1][dt] = MFMA16(pa[1][ks], bg, oacc[1][dt]);
            }
        }
    }

    // rowsums: reduce across G (lanes c, c+16, c+32, c+48 hold same q)
#pragma unroll
    for (int qt = 0; qt < 2; qt++) {
        ps[qt] += __shfl_xor(ps[qt], 16);
        ps[qt] += __shfl_xor(ps[qt], 32);
    }
    float rinv[2][4];
#pragma unroll
    for (int qt = 0; qt < 2; qt++)
#pragma unroll
        for (int i = 0; i < 4; i++)
            rinv[qt][i] = 1.0f / __shfl(ps[qt], 4 * G + i);

    __syncthreads();   // all PV reads of gT_l done before O_l overwrites it

    // normalized O -> O_l [64 q][128 d] bf16, swz key (q&7)<<4
#pragma unroll
    for (int qt = 0; qt < 2; qt++)
#pragma unroll
        for (int dt = 0; dt < 8; dt++)
#pragma unroll
            for (int i = 0; i < 4; i++) {
                int q = w * 32 + qt * 16 + 4 * G + i, d = dt * 16 + c;
                *(unsigned short*)((char*)O_l + q * 256 + ((d * 2) ^ ((q & 7) << 4))) =
                    f2b(oacc[qt][dt][i] * rinv[qt][i]);
            }

    const float sg = *sigma_p;
    const int arow0 = (w * 32 + c) * 256;          // O_l A-frag rows (q = w*32 [+16] + c)
    const int arow1 = (w * 32 + 16 + c) * 256;

    for (int cb = 0; cb < 4; cb++) {
        __syncthreads();                            // O_l writes visible / prev wo_l reads done
#pragma unroll
        for (int it = 0; it < 8; it++) {            // stage woT quarter [64 c][128 d]
            int u = it * 128 + t, r = u >> 4, s = u & 15;
            uint4 v = *(const uint4*)(woT + (size_t)(cb * 64 + r) * 128 + s * 8);
            *(uint4*)((char*)wo_l + r * 256 + ((s * 16) ^ ((r & 7) << 4))) = v;
        }
        __syncthreads();
        f32x4 eacc[2][4];
#pragma unroll
        for (int qt = 0; qt < 2; qt++)
#pragma unroll
            for (int ct = 0; ct < 4; ct++) eacc[qt][ct] = (f32x4){0.f, 0.f, 0.f, 0.f};
#pragma unroll
        for (int ks = 0; ks < 4; ks++) {
            bf16x8 a0 = *(const bf16x8*)((char*)O_l + arow0 + ((ks * 64 + G * 16) ^ xr));
            bf16x8 a1 = *(const bf16x8*)((char*)O_l + arow1 + ((ks * 64 + G * 16) ^ xr));
#pragma unroll
            for (int ct = 0; ct < 4; ct++) {
                int cr = ct * 16 + c;
                bf16x8 bw = *(const bf16x8*)((char*)wo_l + cr * 256 + ((ks * 64 + G * 16) ^ xr));
                eacc[0][ct] = MFMA16(a0, bw, eacc[0][ct]);
                eacc[1][ct] = MFMA16(a1, bw, eacc[1][ct]);
            }
        }
#pragma unroll
        for (int qt = 0; qt < 2; qt++)
#pragma unroll
            for (int ct = 0; ct < 4; ct++) {
                int col = cb * 64 + ct * 16 + c;
                float bo = b_o[col];
#pragma unroll
                for (int i = 0; i < 4; i++) {
                    size_t off = ((size_t)(b * 4096 + q0 + w * 32 + qt * 16 + 4 * G + i)) * 256 + col;
                    out[off] = x[off] + sg * (eacc[qt][ct][i] + bo);
                }
            }
    }
#undef LOAD_CHUNK
}

// ---------------------------------------------------------------------------
extern "C" void kernel_launch(void* const* d_in, const int* in_sizes, int n_in,
                              void* d_out, int out_size, void* d_ws, size_t ws_size,
                              hipStream_t stream)
{
    const float* x       = (const float*)d_in[0];
    const float* w_theta = (const float*)d_in[1];
    const float* w_phi   = (const float*)d_in[2];
    const float* w_g     = (const float*)d_in[3];
    const float* w_o     = (const float*)d_in[4];
    const float* b_o     = (const float*)d_in[5];
    const float* sigma   = (const float*)d_in[6];
    float* out = (float*)d_out;

    char* ws = (char*)d_ws;
    unsigned short* theta_b = (unsigned short*)(ws);              //  4 MB [B,4096,32]
    unsigned short* phi_b   = (unsigned short*)(ws + 4194304);    //  4 MB [B,4096,32]
    unsigned short* g_b     = (unsigned short*)(ws + 8388608);    // 16 MB [B,4096,128]
    unsigned short* phi_p   = (unsigned short*)(ws + 25165824);   //  1 MB [B,1024,32]
    unsigned short* g_pT    = (unsigned short*)(ws + 26214400);   //  4 MB [B,128,1024] (transposed)
    unsigned short* WT      = (unsigned short*)(ws + 30408704);   // 96 KB [192,256]
    unsigned short* woT     = (unsigned short*)(ws + 30507008);   // 64 KB [256,128]

    hipLaunchKernelGGL(k_prep, dim3(448), dim3(256), 0, stream,
                       w_theta, w_phi, w_g, w_o, WT, woT);
    hipLaunchKernelGGL(k_proj, dim3(512), dim3(256), 0, stream,
                       x, WT, theta_b, phi_b, g_b);
    hipLaunchKernelGGL(k_pool, dim3(1536), dim3(256), 0, stream,
                       phi_b, g_b, phi_p, g_pT);
    hipLaunchKernelGGL(k_attn, dim3(1024), dim3(128), 0, stream,
                       theta_b, phi_p, g_pT, woT, x, b_o, sigma, out);
}

// Round 4
// 81.815 us; speedup vs baseline: 9.2748x; 2.0742x over previous
//
#include <hip/hip_runtime.h>
#include <hip/hip_bf16.h>

// SNNonLocalBlock: B=16, H=W=64, C=256, L=4096, Ld=1024
// Round 4: global_load_lds double-buffered k_attn (no register staging -> no spill),
// pre-swizzled global layouts for g_pT/phi_p so linear DMA lands swizzled in LDS.

typedef __attribute__((ext_vector_type(8))) short bf16x8;
typedef __attribute__((ext_vector_type(4))) short bf16x4;
typedef __attribute__((ext_vector_type(4))) float f32x4;

#define MFMA16(A,B,C) __builtin_amdgcn_mfma_f32_16x16x32_bf16(A,B,C,0,0,0)

#define GLOAD16(GSRC, LDST)                                                        \
    __builtin_amdgcn_global_load_lds(                                              \
        (const __attribute__((address_space(1))) unsigned int*)(GSRC),             \
        (__attribute__((address_space(3))) unsigned int*)(LDST), 16, 0, 0)

static __device__ __forceinline__ unsigned short f2b(float f) {
    __hip_bfloat16 h = __float2bfloat16(f);
    return *reinterpret_cast<unsigned short*>(&h);
}
static __device__ __forceinline__ float blo(unsigned int u){ return __uint_as_float(u << 16); }
static __device__ __forceinline__ float bhi(unsigned int u){ return __uint_as_float(u & 0xffff0000u); }

// ---------------------------------------------------------------------------
// K0: prep: WT[192 n][256 k] bf16 = [w_theta|w_phi|w_g]^T ; woT[256 c][128 d] bf16
// ---------------------------------------------------------------------------
__global__ void k_prep(const float* __restrict__ w_theta, const float* __restrict__ w_phi,
                       const float* __restrict__ w_g, const float* __restrict__ w_o,
                       unsigned short* __restrict__ WT, unsigned short* __restrict__ woT)
{
    int bid = blockIdx.x, t = threadIdx.x;
    if (bid < 192) {
        int n = bid;
        float v;
        if (n < 32)      v = w_theta[t * 32 + n];
        else if (n < 64) v = w_phi[t * 32 + (n - 32)];
        else             v = w_g[t * 128 + (n - 64)];
        WT[n * 256 + t] = f2b(v);
    } else if (t < 128) {
        int cc = bid - 192;
        woT[cc * 128 + t] = f2b(w_o[t * 256 + cc]);
    }
}

// ---------------------------------------------------------------------------
// K1: proj MFMA: out[65536,192] = x @ W. 128-row blocks, BK=64, 4 waves.
// ---------------------------------------------------------------------------
__global__ __launch_bounds__(256) void k_proj(
    const float* __restrict__ x, const unsigned short* __restrict__ WT,
    unsigned short* __restrict__ theta_b, unsigned short* __restrict__ phi_b,
    unsigned short* __restrict__ g_b)
{
    __shared__ unsigned short xT[128 * 64];   // [m][64k] swizzled, 16KB
    __shared__ unsigned short wT[192 * 64];   // [n][64k] swizzled, 24KB
    const int t = threadIdx.x;
    const int w = t >> 6, l = t & 63, G = l >> 4, c = l & 15;
    const size_t row0 = (size_t)blockIdx.x * 128;

    f32x4 acc[2][12];
#pragma unroll
    for (int i = 0; i < 2; i++)
#pragma unroll
        for (int j = 0; j < 12; j++) acc[i][j] = (f32x4){0.f, 0.f, 0.f, 0.f};

    for (int k0 = 0; k0 < 256; k0 += 64) {
        __syncthreads();
#pragma unroll
        for (int it = 0; it < 4; it++) {           // x tile: 128 rows x 8 slots
            int u = it * 256 + t, r = u >> 3, s = u & 7;
            const float* px = x + (row0 + r) * 256 + k0 + s * 8;
            float4 a = *(const float4*)px;
            float4 bq = *(const float4*)(px + 4);
            uint4 v;
            v.x = (unsigned)f2b(a.x) | ((unsigned)f2b(a.y) << 16);
            v.y = (unsigned)f2b(a.z) | ((unsigned)f2b(a.w) << 16);
            v.z = (unsigned)f2b(bq.x) | ((unsigned)f2b(bq.y) << 16);
            v.w = (unsigned)f2b(bq.z) | ((unsigned)f2b(bq.w) << 16);
            *(uint4*)((char*)xT + r * 128 + ((s * 16) ^ ((r & 7) << 4))) = v;
        }
#pragma unroll
        for (int it = 0; it < 6; it++) {           // W tile: 192 rows x 8 slots
            int u = it * 256 + t, r = u >> 3, s = u & 7;
            uint4 v = *(const uint4*)(WT + r * 256 + k0 + s * 8);
            *(uint4*)((char*)wT + r * 128 + ((s * 16) ^ ((r & 7) << 4))) = v;
        }
        __syncthreads();
#pragma unroll
        for (int kin = 0; kin < 2; kin++) {
            int m0r = (2 * w) * 16 + c, m1r = (2 * w + 1) * 16 + c;
            bf16x8 a0 = *(const bf16x8*)((char*)xT + m0r * 128 + ((kin * 64 + G * 16) ^ ((m0r & 7) << 4)));
            bf16x8 a1 = *(const bf16x8*)((char*)xT + m1r * 128 + ((kin * 64 + G * 16) ^ ((m1r & 7) << 4)));
#pragma unroll
            for (int nt = 0; nt < 12; nt++) {
                int nr = nt * 16 + c;
                bf16x8 bv = *(const bf16x8*)((char*)wT + nr * 128 + ((kin * 64 + G * 16) ^ ((nr & 7) << 4)));
                acc[0][nt] = MFMA16(a0, bv, acc[0][nt]);
                acc[1][nt] = MFMA16(a1, bv, acc[1][nt]);
            }
        }
    }
#pragma unroll
    for (int mt = 0; mt < 2; mt++)
#pragma unroll
        for (int nt = 0; nt < 12; nt++)
#pragma unroll
            for (int i = 0; i < 4; i++) {
                size_t row = row0 + (2 * w + mt) * 16 + 4 * G + i;
                unsigned short v = f2b(acc[mt][nt][i]);
                if (nt < 2)      theta_b[row * 32 + nt * 16 + c] = v;
                else if (nt < 4) phi_b[row * 32 + (nt - 2) * 16 + c] = v;
                else             g_b[row * 128 + (nt - 4) * 16 + c] = v;
            }
}

// ---------------------------------------------------------------------------
// K2: pool. blocks [0,1024): phi -> phi_p [b][1024][32] PRE-SWIZZLED
//            (16B blk within 64B row XOR'd by (m&3): u32 idx d2 ^= (m&3)<<2)
//          blocks [1024,1536): g -> pooled + transposed g_pT [b][128 d][1024 m]
//            PRE-SWIZZLED (16B blk within each 128B m-group XOR'd by d&7:
//             m idx ^= (d&7)<<3)
// ---------------------------------------------------------------------------
__global__ __launch_bounds__(256) void k_pool(
    const unsigned short* __restrict__ phi_b, const unsigned short* __restrict__ g_b,
    unsigned short* __restrict__ phi_p, unsigned short* __restrict__ g_pT)
{
    const int bid = blockIdx.x, t = threadIdx.x;
    if (bid < 1024) {
        const unsigned int* p32 = (const unsigned int*)phi_b;
        unsigned int* pp32 = (unsigned int*)phi_p;
        int idx = bid * 256 + t;
        int b = idx >> 14, r = idx & 16383, pm = r >> 4, d2 = r & 15;
        int hp = pm >> 5, wp = pm & 31;
        size_t base = ((size_t)b * 4096 + (2 * hp) * 64 + 2 * wp) * 16 + d2;
        unsigned v0 = p32[base], v1 = p32[base + 16], v2 = p32[base + 1024], v3 = p32[base + 1040];
        float lo = fmaxf(fmaxf(blo(v0), blo(v1)), fmaxf(blo(v2), blo(v3)));
        float hi = fmaxf(fmaxf(bhi(v0), bhi(v1)), fmaxf(bhi(v2), bhi(v3)));
        pp32[(idx & ~15) | (d2 ^ ((pm & 3) << 2))] =
            (unsigned)f2b(lo) | ((unsigned)f2b(hi) << 16);
    } else {
        __shared__ unsigned short P[32 * 128];   // [wp][128 d], rows 256B, swz key (wp&7)<<4
        int b = (bid - 1024) >> 5, hp = (bid - 1024) & 31;
        const unsigned int* g32 = (const unsigned int*)g_b;
#pragma unroll
        for (int it = 0; it < 8; it++) {
            int u = it * 256 + t, wp = u >> 6, d2 = u & 63;
            size_t base = ((size_t)b * 4096 + (2 * hp) * 64 + 2 * wp) * 64 + d2;
            unsigned v0 = g32[base], v1 = g32[base + 64], v2 = g32[base + 4096], v3 = g32[base + 4160];
            float lo = fmaxf(fmaxf(blo(v0), blo(v1)), fmaxf(blo(v2), blo(v3)));
            float hi = fmaxf(fmaxf(bhi(v0), bhi(v1)), fmaxf(bhi(v2), bhi(v3)));
            unsigned pv = (unsigned)f2b(lo) | ((unsigned)f2b(hi) << 16);
            *(unsigned*)((char*)P + wp * 256 + ((d2 * 4) ^ ((wp & 7) << 4))) = pv;
        }
        __syncthreads();
#pragma unroll
        for (int it = 0; it < 2; it++) {
            int d = t & 127, s4 = (t >> 7) + it * 2;
            union { unsigned short v[8]; uint4 q; } pk;
#pragma unroll
            for (int k = 0; k < 8; k++) {
                int wp = s4 * 8 + k;
                pk.v[k] = *(const unsigned short*)((char*)P + wp * 256 + ((d * 2) ^ ((wp & 7) << 4)));
            }
            int midx = (hp * 32 + s4 * 8) ^ ((d & 7) << 3);   // pre-swizzle m blocks
            *(uint4*)(g_pT + ((size_t)b * 128 + d) * 1024 + midx) = pk.q;
        }
    }
}

// ---------------------------------------------------------------------------
// K3: fused flash attention. 128 threads (2 waves), 64 q rows, 16 m-chunks of 64.
// Double-buffered LDS staged via global_load_lds; counted vmcnt(10).
// ---------------------------------------------------------------------------
__global__ __launch_bounds__(128, 2) void k_attn(
    const unsigned short* __restrict__ theta_b, const unsigned short* __restrict__ phi_p,
    const unsigned short* __restrict__ g_pT, const unsigned short* __restrict__ woT,
    const float* __restrict__ x, const float* __restrict__ b_o,
    const float* __restrict__ sigma_p, float* __restrict__ out)
{
    // layout: buf0 @0 (g 16KB | phi 4KB @16384), buf1 @20480 (g | phi @36864)
    // theta staged in buf1.phi region (4KB). Epilogue: O_l @0 (16KB), wo_l @20480 (16KB).
    __shared__ char lds[40960];

    const int t = threadIdx.x;
    const int w = t >> 6, l = t & 63, G = l >> 4, c = l & 15;
    const int bid = (blockIdx.x & 7) * 128 + (blockIdx.x >> 3);   // XCD swizzle (bijective)
    const int b = bid >> 6;
    const int q0 = (bid & 63) * 64;
    const int xr = (c & 7) << 4;       // 128B-row swizzle key (rows with row&7 == c&7)
    const int xr3 = (c & 3) << 4;      // 64B-row swizzle key

    // stage target helper: issue 10 global_load_lds per wave for chunk mcn into buf bi
    const unsigned short* gsrc_base = g_pT + (size_t)b * 131072;
    const unsigned short* psrc_base = phi_p + (size_t)b * 32768;
#define STAGE(BI, MCN)                                                                  \
    {                                                                                   \
        char* gb = lds + (BI) * 20480;                                                  \
        char* pb = gb + 16384;                                                          \
        _Pragma("unroll")                                                               \
        for (int it = 0; it < 8; it++) {                                                \
            int d = (it * 128 + t) >> 3, s = t & 7;                                     \
            GLOAD16(gsrc_base + (size_t)d * 1024 + (MCN) * 64 + s * 8,                  \
                    gb + it * 2048 + w * 1024);                                         \
        }                                                                               \
        _Pragma("unroll")                                                               \
        for (int it = 0; it < 2; it++) {                                                \
            int u = it * 128 + t, r = u >> 2, s = u & 3;                                \
            GLOAD16(psrc_base + (size_t)((MCN) * 64 + r) * 32 + s * 8,                  \
                    pb + it * 2048 + w * 1024);                                         \
        }                                                                               \
    }

    // prologue: stage chunk 0 + theta (theta in buf1.phi region, swizzled 64B rows)
    STAGE(0, 0);
    {
        char* th = lds + 36864;
#pragma unroll
        for (int it = 0; it < 2; it++) {
            int u = it * 128 + t, r = u >> 2, s = u & 3;
            uint4 v = *(const uint4*)(theta_b + ((size_t)(b * 4096 + q0 + r)) * 32 + s * 8);
            *(uint4*)(th + r * 64 + ((s * 16) ^ ((r & 3) << 4))) = v;
        }
    }
    __syncthreads();   // drains vmcnt+lgkm: chunk0 + theta in LDS

    // theta B-frags (loop-invariant, consumed to regs before buf1 is overwritten)
    bf16x8 bt0, bt1;
    {
        const char* th = lds + 36864;
        bt0 = *(const bf16x8*)(th + (w * 32 + c) * 64 + ((G * 16) ^ xr3));
        bt1 = *(const bf16x8*)(th + (w * 32 + 16 + c) * 64 + ((G * 16) ^ xr3));
    }
    __syncthreads();   // all bt reads complete before iter0 stages buf1

    f32x4 oacc[2][8];
#pragma unroll
    for (int qt = 0; qt < 2; qt++)
#pragma unroll
        for (int dt = 0; dt < 8; dt++) oacc[qt][dt] = (f32x4){0.f, 0.f, 0.f, 0.f};
    float ps[2] = {0.f, 0.f};
    const f32x4 zf = (f32x4){0.f, 0.f, 0.f, 0.f};

    for (int mc = 0; mc < 16; mc++) {
        const int cur = mc & 1;
        if (mc < 15) {
            STAGE(cur ^ 1, mc + 1);                       // next chunk in flight
            asm volatile("s_waitcnt vmcnt(10)" ::: "memory");   // cur's 10 landed
        } else {
            asm volatile("s_waitcnt vmcnt(0)" ::: "memory");
        }
        __builtin_amdgcn_sched_barrier(0);
        __builtin_amdgcn_s_barrier();                     // both waves' cur landed
        __builtin_amdgcn_sched_barrier(0);

        const char* gL   = lds + cur * 20480;
        const char* phiL = gL + 16384;

        // S^T = phi @ theta^T : lane (G,c) gets S[m = mt*16+4G+i][q = c]
        bf16x8 ap[4];
#pragma unroll
        for (int mt = 0; mt < 4; mt++)
            ap[mt] = *(const bf16x8*)(phiL + (mt * 16 + c) * 64 + ((G * 16) ^ xr3));
        f32x4 sacc[2][4];
        __builtin_amdgcn_s_setprio(1);
#pragma unroll
        for (int mt = 0; mt < 4; mt++) {
            sacc[0][mt] = MFMA16(ap[mt], bt0, zf);
            sacc[1][mt] = MFMA16(ap[mt], bt1, zf);
        }
        __builtin_amdgcn_s_setprio(0);

        // exp (no max-sub: |S| << 88) -> packed P A-frags + rowsum partials
        bf16x8 pa[2][2];
#pragma unroll
        for (int qt = 0; qt < 2; qt++) {
#pragma unroll
            for (int ks = 0; ks < 2; ks++) {
                union { unsigned u[4]; bf16x8 v; } pu;
#pragma unroll
                for (int hf = 0; hf < 2; hf++) {
                    int mt = 2 * ks + hf;
                    float p0 = __expf(sacc[qt][mt][0]);
                    float p1 = __expf(sacc[qt][mt][1]);
                    float p2 = __expf(sacc[qt][mt][2]);
                    float p3 = __expf(sacc[qt][mt][3]);
                    ps[qt] += (p0 + p1) + (p2 + p3);
                    pu.u[hf * 2]     = (unsigned)f2b(p0) | ((unsigned)f2b(p1) << 16);
                    pu.u[hf * 2 + 1] = (unsigned)f2b(p2) | ((unsigned)f2b(p3) << 16);
                }
                pa[qt][ks] = pu.v;
            }
        }

        // O += P @ g
        __builtin_amdgcn_s_setprio(1);
#pragma unroll
        for (int ks = 0; ks < 2; ks++) {
#pragma unroll
            for (int dt = 0; dt < 8; dt++) {
                const char* rb = gL + (dt * 16 + c) * 128;
                bf16x4 x0 = *(const bf16x4*)(rb + ((64 * ks + 8 * G) ^ xr));
                bf16x4 x1 = *(const bf16x4*)(rb + ((64 * ks + 32 + 8 * G) ^ xr));
                bf16x8 bg = __builtin_shufflevector(x0, x1, 0, 1, 2, 3, 4, 5, 6, 7);
                oacc[0][dt] = MFMA16(pa[0][ks], bg, oacc[0][dt]);
                oacc[1][dt] = MFMA16(pa[1][ks], bg, oacc[1][dt]);
            }
        }
        __builtin_amdgcn_s_setprio(0);

        asm volatile("s_waitcnt lgkmcnt(0)" ::: "memory");  // cur reads done (vmcnt stays)
        __builtin_amdgcn_sched_barrier(0);
        __builtin_amdgcn_s_barrier();                       // safe to overwrite cur next iter
        __builtin_amdgcn_sched_barrier(0);
    }
#undef STAGE

    // rowsums: reduce across G (lanes c, c+16, c+32, c+48 hold same q=c)
#pragma unroll
    for (int qt = 0; qt < 2; qt++) {
        ps[qt] += __shfl_xor(ps[qt], 16);
        ps[qt] += __shfl_xor(ps[qt], 32);
    }
    float rinv[2][4];
#pragma unroll
    for (int qt = 0; qt < 2; qt++)
#pragma unroll
        for (int i = 0; i < 4; i++)
            rinv[qt][i] = 1.0f / __shfl(ps[qt], 4 * G + i);

    // normalized O -> O_l [64 q][128 d] bf16 @0 (buf0; all buf0 readers finished)
    char* O_l = lds;
#pragma unroll
    for (int qt = 0; qt < 2; qt++)
#pragma unroll
        for (int dt = 0; dt < 8; dt++)
#pragma unroll
            for (int i = 0; i < 4; i++) {
                int q = w * 32 + qt * 16 + 4 * G + i, d = dt * 16 + c;
                *(unsigned short*)(O_l + q * 256 + ((d * 2) ^ ((q & 7) << 4))) =
                    f2b(oacc[qt][dt][i] * rinv[qt][i]);
            }

    const float sg = *sigma_p;
    char* wo_l = lds + 20480;
    const int arow0 = (w * 32 + c) * 256;
    const int arow1 = (w * 32 + 16 + c) * 256;

    for (int cb = 0; cb < 4; cb++) {
        __syncthreads();                            // O_l visible / prev wo_l reads done
#pragma unroll
        for (int it = 0; it < 8; it++) {            // stage woT quarter [64 c][128 d]
            int u = it * 128 + t, r = u >> 4, s = u & 15;
            uint4 v = *(const uint4*)(woT + (size_t)(cb * 64 + r) * 128 + s * 8);
            *(uint4*)(wo_l + r * 256 + ((s * 16) ^ ((r & 7) << 4))) = v;
        }
        __syncthreads();
        f32x4 eacc[2][4];
#pragma unroll
        for (int qt = 0; qt < 2; qt++)
#pragma unroll
            for (int ct = 0; ct < 4; ct++) eacc[qt][ct] = (f32x4){0.f, 0.f, 0.f, 0.f};
#pragma unroll
        for (int ks = 0; ks < 4; ks++) {
            bf16x8 a0 = *(const bf16x8*)(O_l + arow0 + ((ks * 64 + G * 16) ^ xr));
            bf16x8 a1 = *(const bf16x8*)(O_l + arow1 + ((ks * 64 + G * 16) ^ xr));
#pragma unroll
            for (int ct = 0; ct < 4; ct++) {
                int cr = ct * 16 + c;
                bf16x8 bw = *(const bf16x8*)(wo_l + cr * 256 + ((ks * 64 + G * 16) ^ xr));
                eacc[0][ct] = MFMA16(a0, bw, eacc[0][ct]);
                eacc[1][ct] = MFMA16(a1, bw, eacc[1][ct]);
            }
        }
#pragma unroll
        for (int qt = 0; qt < 2; qt++)
#pragma unroll
            for (int ct = 0; ct < 4; ct++) {
                int col = cb * 64 + ct * 16 + c;
                float bo = b_o[col];
#pragma unroll
                for (int i = 0; i < 4; i++) {
                    size_t off = ((size_t)(b * 4096 + q0 + w * 32 + qt * 16 + 4 * G + i)) * 256 + col;
                    out[off] = x[off] + sg * (eacc[qt][ct][i] + bo);
                }
            }
    }
}

// ---------------------------------------------------------------------------
extern "C" void kernel_launch(void* const* d_in, const int* in_sizes, int n_in,
                              void* d_out, int out_size, void* d_ws, size_t ws_size,
                              hipStream_t stream)
{
    const float* x       = (const float*)d_in[0];
    const float* w_theta = (const float*)d_in[1];
    const float* w_phi   = (const float*)d_in[2];
    const float* w_g     = (const float*)d_in[3];
    const float* w_o     = (const float*)d_in[4];
    const float* b_o     = (const float*)d_in[5];
    const float* sigma   = (const float*)d_in[6];
    float* out = (float*)d_out;

    char* ws = (char*)d_ws;
    unsigned short* theta_b = (unsigned short*)(ws);              //  4 MB [B,4096,32]
    unsigned short* phi_b   = (unsigned short*)(ws + 4194304);    //  4 MB [B,4096,32]
    unsigned short* g_b     = (unsigned short*)(ws + 8388608);    // 16 MB [B,4096,128]
    unsigned short* phi_p   = (unsigned short*)(ws + 25165824);   //  1 MB [B,1024,32] pre-swz
    unsigned short* g_pT    = (unsigned short*)(ws + 26214400);   //  4 MB [B,128,1024] pre-swz
    unsigned short* WT      = (unsigned short*)(ws + 30408704);   // 96 KB [192,256]
    unsigned short* woT     = (unsigned short*)(ws + 30507008);   // 64 KB [256,128]

    hipLaunchKernelGGL(k_prep, dim3(448), dim3(256), 0, stream,
                       w_theta, w_phi, w_g, w_o, WT, woT);
    hipLaunchKernelGGL(k_proj, dim3(512), dim3(256), 0, stream,
                       x, WT, theta_b, phi_b, g_b);
    hipLaunchKernelGGL(k_pool, dim3(1536), dim3(256), 0, stream,
                       phi_b, g_b, phi_p, g_pT);
    hipLaunchKernelGGL(k_attn, dim3(1024), dim3(128), 0, stream,
                       theta_b, phi_p, g_pT, woT, x, b_o, sigma, out);
}